// Round 1
// baseline (521.000 us; speedup 1.0000x reference)
//
#include <hip/hip_runtime.h>

#define B_ 8
#define N_ 16384
#define S_ 1024
#define K_ 32
#define CSTEM 64
#define CPATCH 128
#define INDIM 91   // CSTEM + 3 + 24

// -------- Kernel 1: ball query (one wave per (b,s) query) --------
// Reference semantics: the K smallest-index points with d^2 <= r^2,
// padded with the first found index (or N-1 if none found).
__global__ __launch_bounds__(64) void ball_query_kernel(
    const float* __restrict__ xyz, const float* __restrict__ pc,
    float* __restrict__ idx_out)
{
  const int bs = blockIdx.x;          // b*S + s
  const int b  = bs >> 10;            // S_ = 1024
  const int lane = threadIdx.x;       // 0..63

  const float* __restrict__ xb = xyz + (size_t)b * N_ * 3;
  const double cx = (double)pc[bs * 3 + 0];
  const double cy = (double)pc[bs * 3 + 1];
  const double cz = (double)pc[bs * 3 + 2];
  const double rr = 0.2 * 0.2;

  __shared__ int fidx[K_];

  int found = 0;
  for (int base = 0; base < N_; base += 64) {
    const int i = base + lane;
    const double dx = (double)xb[i * 3 + 0] - cx;
    const double dy = (double)xb[i * 3 + 1] - cy;
    const double dz = (double)xb[i * 3 + 2] - cz;
    const double d2 = dx * dx + dy * dy + dz * dz;
    const bool in = (d2 <= rr);
    const unsigned long long m = __ballot(in);
    const int before = __popcll(m & ((1ull << lane) - 1ull));
    const int pos = found + before;
    if (in && pos < K_) fidx[pos] = i;
    found += __popcll(m);
    if (found >= K_) break;
  }
  __syncthreads();
  if (lane < K_) {
    const int fill = (found == 0) ? (N_ - 1) : fidx[0];
    const int v = (lane < found) ? fidx[lane] : fill;
    idx_out[(size_t)bs * K_ + lane] = (float)v;  // harness reads outputs as float
  }
}

// -------- Kernel 2: gather + PE + MLP(91->128 relu ->128) + max over K --------
// One block (128 threads) per patch; thread = output channel.
// 32 row-accumulators in VGPRs so each weight element is read once per block.
__global__ __launch_bounds__(128) void patch_mlp_kernel(
    const float* __restrict__ xyz, const float* __restrict__ pf,
    const float* __restrict__ pc,
    const float* __restrict__ w1, const float* __restrict__ b1,
    const float* __restrict__ w2, const float* __restrict__ b2,
    const float* __restrict__ idx_f, float* __restrict__ out)
{
  const int bs  = blockIdx.x;
  const int b   = bs >> 10;
  const int tid = threadIdx.x;   // 0..127

  __shared__ int sidx[K_];
  __shared__ __align__(16) float sgi[K_][92];       // k-major, padded col 91 = 0
  __shared__ __align__(16) float sh1[K_][CPATCH];
  __shared__ float scen[3];

  if (tid < K_) sidx[tid] = (int)idx_f[(size_t)bs * K_ + tid];
  if (tid < 3)  scen[tid] = pc[bs * 3 + tid];
  if (tid < K_) sgi[tid][91] = 0.f;
  __syncthreads();

  const float* __restrict__ pfb = pf  + (size_t)b * N_ * CSTEM;
  const float* __restrict__ xb  = xyz + (size_t)b * N_ * 3;

  // Producer: grouped_input = [feature(64) | rel(3) | pe(24)] per neighbor row.
  for (int k = 0; k < K_; ++k) {
    const int row = sidx[k];
    if (tid < CSTEM) {
      sgi[k][tid] = pfb[(size_t)row * CSTEM + tid];        // coalesced 256B
    } else if (tid < INDIM) {
      const int i = tid - CSTEM;    // 0..26
      float v;
      if (i < 3) {
        v = xb[row * 3 + i] - scen[i];
      } else {
        const int j = i - 3;        // 0..23
        const int d = j >> 3;       // xyz dim
        const int r = j & 7;        // 0..7: [sin f0..f3 | cos f0..f3]
        const int band = r & 3;
        const float rel = xb[row * 3 + d] - scen[d];
        const float ang = rel * ((float)(1 << band) * 3.14159265358979323846f);
        v = (r < 4) ? sinf(ang) : cosf(ang);
      }
      sgi[k][tid] = v;
    }
  }
  __syncthreads();

  // Layer 1: h1[k][c] = relu(b1[c] + sum_i gi[k][i] * w1[i][c])
  float acc[K_];
  const float bias1 = b1[tid];
  #pragma unroll
  for (int k = 0; k < K_; ++k) acc[k] = bias1;

  for (int i4 = 0; i4 < 23; ++i4) {                // 23*4 = 92 (col 91 is zero pad)
    const int i = i4 * 4;
    const float wa = w1[(i + 0) * CPATCH + tid];
    const float wb = w1[(i + 1) * CPATCH + tid];
    const float wc = w1[(i + 2) * CPATCH + tid];
    const float wd = (i + 3 < INDIM) ? w1[(i + 3) * CPATCH + tid] : 0.f;
    #pragma unroll
    for (int k = 0; k < K_; ++k) {
      const float4 g = *(const float4*)&sgi[k][i];  // broadcast read
      acc[k] += g.x * wa + g.y * wb + g.z * wc + g.w * wd;
    }
  }

  #pragma unroll
  for (int k = 0; k < K_; ++k) sh1[k][tid] = fmaxf(acc[k], 0.f);
  __syncthreads();

  // Layer 2 + max over k
  float acc2[K_];
  const float bias2 = b2[tid];
  #pragma unroll
  for (int k = 0; k < K_; ++k) acc2[k] = bias2;

  for (int i4 = 0; i4 < CPATCH / 4; ++i4) {
    const int i = i4 * 4;
    const float wa = w2[(i + 0) * CPATCH + tid];
    const float wb = w2[(i + 1) * CPATCH + tid];
    const float wc = w2[(i + 2) * CPATCH + tid];
    const float wd = w2[(i + 3) * CPATCH + tid];
    #pragma unroll
    for (int k = 0; k < K_; ++k) {
      const float4 g = *(const float4*)&sh1[k][i];  // broadcast read
      acc2[k] += g.x * wa + g.y * wb + g.z * wc + g.w * wd;
    }
  }

  float m = acc2[0];
  #pragma unroll
  for (int k = 1; k < K_; ++k) m = fmaxf(m, acc2[k]);
  out[(size_t)bs * CPATCH + tid] = m;
}

extern "C" void kernel_launch(void* const* d_in, const int* in_sizes, int n_in,
                              void* d_out, int out_size, void* d_ws, size_t ws_size,
                              hipStream_t stream) {
  const float* xyz = (const float*)d_in[0];
  const float* pf  = (const float*)d_in[1];
  const float* pc  = (const float*)d_in[2];
  const float* w1  = (const float*)d_in[3];
  const float* b1  = (const float*)d_in[4];
  const float* w2  = (const float*)d_in[5];
  const float* b2  = (const float*)d_in[6];

  float* out     = (float*)d_out;
  float* idx_out = out + (size_t)B_ * S_ * CPATCH;   // second output region

  ball_query_kernel<<<B_ * S_, 64, 0, stream>>>(xyz, pc, idx_out);
  patch_mlp_kernel<<<B_ * S_, 128, 0, stream>>>(xyz, pf, pc, w1, b1, w2, b2,
                                                idx_out, out);
}

// Round 2
// 66.119 us; speedup vs baseline: 7.8797x; 7.8797x over previous
//
#include <hip/hip_runtime.h>
#include <hip/hip_bf16.h>

#define B_ 8
#define N_ 16384
#define S_ 1024
#define K_ 32
#define CSTEM 64
#define CPATCH 128
#define INDIM 91
#define LDA 104   // LDS row stride (bf16) for A tile: 208B -> 2-way (free) on b128 reads
#define LDH 136   // LDS row stride (bf16) for h1 tile: 272B -> 2-way (free)

typedef __attribute__((ext_vector_type(8))) short short8v;  // 8 bf16 = 4 VGPRs
typedef __attribute__((ext_vector_type(4))) float f32x4;

static __device__ __forceinline__ unsigned short f2bf(float f) {
  union { float f; unsigned int u; } v; v.f = f;
  return (unsigned short)((v.u + 0x7FFFu + ((v.u >> 16) & 1u)) >> 16);  // RNE
}

// -------- Kernel 0: pack w1/w2 into MFMA B-fragment order (bf16) --------
// B-frag layout (16x16x32): lane l holds col=16*ct+(l&15), k=32*ks+(l>>4)*8+j.
// Packed: [ks][ct][lane][8] so each lane's fragment is one contiguous 16B load.
__global__ __launch_bounds__(256) void pack_weights(
    const float* __restrict__ w1, const float* __restrict__ w2,
    unsigned short* __restrict__ w1p, unsigned short* __restrict__ w2p)
{
  const int id = blockIdx.x * 256 + threadIdx.x;
  if (id < 3 * 8 * 64) {                       // w1: K padded 91->96 (3 ksteps)
    const int l = id & 63, ct = (id >> 6) & 7, ks = id >> 9;
    const int col = 16 * ct + (l & 15);
    const int kb = 32 * ks + (l >> 4) * 8;
    unsigned short v[8];
    #pragma unroll
    for (int j = 0; j < 8; ++j) {
      const int k = kb + j;
      v[j] = (k < INDIM) ? f2bf(w1[k * CPATCH + col]) : (unsigned short)0;
    }
    *(short8v*)&w1p[(size_t)id * 8] = *(const short8v*)v;
  } else if (id < 3 * 8 * 64 + 4 * 8 * 64) {   // w2: 4 ksteps
    const int id2 = id - 3 * 8 * 64;
    const int l = id2 & 63, ct = (id2 >> 6) & 7, ks = id2 >> 9;
    const int col = 16 * ct + (l & 15);
    const int kb = 32 * ks + (l >> 4) * 8;
    unsigned short v[8];
    #pragma unroll
    for (int j = 0; j < 8; ++j) v[j] = f2bf(w2[(kb + j) * CPATCH + col]);
    *(short8v*)&w2p[(size_t)id2 * 8] = *(const short8v*)v;
  }
}

// -------- Kernel 1: ball query (unchanged from passing R1) --------
__global__ __launch_bounds__(64) void ball_query_kernel(
    const float* __restrict__ xyz, const float* __restrict__ pc,
    float* __restrict__ idx_out)
{
  const int bs = blockIdx.x;
  const int b  = bs >> 10;
  const int lane = threadIdx.x;

  const float* __restrict__ xb = xyz + (size_t)b * N_ * 3;
  const double cx = (double)pc[bs * 3 + 0];
  const double cy = (double)pc[bs * 3 + 1];
  const double cz = (double)pc[bs * 3 + 2];
  const double rr = 0.2 * 0.2;

  __shared__ int fidx[K_];

  int found = 0;
  for (int base = 0; base < N_; base += 64) {
    const int i = base + lane;
    const double dx = (double)xb[i * 3 + 0] - cx;
    const double dy = (double)xb[i * 3 + 1] - cy;
    const double dz = (double)xb[i * 3 + 2] - cz;
    const double d2 = dx * dx + dy * dy + dz * dz;
    const bool in = (d2 <= rr);
    const unsigned long long m = __ballot(in);
    const int before = __popcll(m & ((1ull << lane) - 1ull));
    const int pos = found + before;
    if (in && pos < K_) fidx[pos] = i;
    found += __popcll(m);
    if (found >= K_) break;
  }
  __syncthreads();
  if (lane < K_) {
    const int fill = (found == 0) ? (N_ - 1) : fidx[0];
    const int v = (lane < found) ? fidx[lane] : fill;
    idx_out[(size_t)bs * K_ + lane] = (float)v;
  }
}

// -------- Kernel 2: gather + PE + bf16-MFMA MLP + max --------
// One 256-thread block (4 waves) per patch. Wave w owns output cols [32w,32w+32).
__global__ __launch_bounds__(256) void patch_mlp_mfma(
    const float* __restrict__ xyz, const float* __restrict__ pf,
    const float* __restrict__ pc,
    const unsigned short* __restrict__ w1p, const float* __restrict__ b1,
    const unsigned short* __restrict__ w2p, const float* __restrict__ b2,
    const float* __restrict__ idx_f, float* __restrict__ out)
{
  const int bs   = blockIdx.x;
  const int b    = bs >> 10;
  const int tid  = threadIdx.x;
  const int lane = tid & 63;
  const int w    = tid >> 6;

  __shared__ int sidx[K_];
  __shared__ float scen[3];
  __shared__ __align__(16) unsigned short As[K_][LDA];
  __shared__ __align__(16) unsigned short Hs[K_][LDH];

  if (tid < K_) sidx[tid] = (int)idx_f[(size_t)bs * K_ + tid];
  if (tid < 3)  scen[tid] = pc[bs * 3 + tid];
  __syncthreads();

  const float* __restrict__ pfb = pf  + (size_t)b * N_ * CSTEM;
  const float* __restrict__ xb  = xyz + (size_t)b * N_ * 3;

  // Phase 1: grouped features -> As[row][0..63] (bf16). 8 threads per row.
  {
    const int row = tid >> 3, sub = tid & 7;
    const int r = sidx[row];
    const float4 f0 = *(const float4*)&pfb[(size_t)r * CSTEM + sub * 8];
    const float4 f1 = *(const float4*)&pfb[(size_t)r * CSTEM + sub * 8 + 4];
    unsigned short v[8];
    v[0] = f2bf(f0.x); v[1] = f2bf(f0.y); v[2] = f2bf(f0.z); v[3] = f2bf(f0.w);
    v[4] = f2bf(f1.x); v[5] = f2bf(f1.y); v[6] = f2bf(f1.z); v[7] = f2bf(f1.w);
    *(short8v*)&As[row][sub * 8] = *(const short8v*)v;
  }
  // Phase 2: rel(3) + PE(24) + pad(5) -> As[row][64..95]. 8 threads x 4 cols per row.
  {
    const int row = tid & 31, j = tid >> 5;
    const int r = sidx[row];
    float rel[3];
    rel[0] = xb[r * 3 + 0] - scen[0];
    rel[1] = xb[r * 3 + 1] - scen[1];
    rel[2] = xb[r * 3 + 2] - scen[2];
    #pragma unroll
    for (int cc = 0; cc < 4; ++cc) {
      const int c = 64 + 4 * j + cc;
      float val;
      if (c < 67) val = rel[c - 64];
      else if (c < 91) {
        const int q = c - 67, d = q >> 3, rbit = q & 7, band = rbit & 3;
        const float ang = rel[d] * ((float)(1 << band) * 3.14159265358979323846f);
        val = (rbit < 4) ? sinf(ang) : cosf(ang);
      } else val = 0.f;
      As[row][c] = f2bf(val);
    }
  }
  __syncthreads();

  // Layer 1: 32x96 @ 96x128, wave w computes cols [32w, 32w+32)
  f32x4 acc[2][2] = {};
  #pragma unroll
  for (int ks = 0; ks < 3; ++ks) {
    const int k0 = ks * 32 + (lane >> 4) * 8;
    const short8v a0 = *(const short8v*)&As[(lane & 15)][k0];
    const short8v a1 = *(const short8v*)&As[16 + (lane & 15)][k0];
    const short8v bA = *(const short8v*)&w1p[((size_t)(ks * 8 + 2 * w) * 64 + lane) * 8];
    const short8v bB = *(const short8v*)&w1p[((size_t)(ks * 8 + 2 * w + 1) * 64 + lane) * 8];
    acc[0][0] = __builtin_amdgcn_mfma_f32_16x16x32_bf16(a0, bA, acc[0][0], 0, 0, 0);
    acc[0][1] = __builtin_amdgcn_mfma_f32_16x16x32_bf16(a0, bB, acc[0][1], 0, 0, 0);
    acc[1][0] = __builtin_amdgcn_mfma_f32_16x16x32_bf16(a1, bA, acc[1][0], 0, 0, 0);
    acc[1][1] = __builtin_amdgcn_mfma_f32_16x16x32_bf16(a1, bB, acc[1][1], 0, 0, 0);
  }
  const float bias1[2] = { b1[32 * w + (lane & 15)], b1[32 * w + 16 + (lane & 15)] };
  #pragma unroll
  for (int rt = 0; rt < 2; ++rt)
    #pragma unroll
    for (int t = 0; t < 2; ++t)
      #pragma unroll
      for (int reg = 0; reg < 4; ++reg) {
        const float h = fmaxf(acc[rt][t][reg] + bias1[t], 0.f);
        const int row = 16 * rt + (lane >> 4) * 4 + reg;
        const int col = 32 * w + 16 * t + (lane & 15);
        Hs[row][col] = f2bf(h);
      }
  __syncthreads();

  // Layer 2: 32x128 @ 128x128 + column max over the 32 rows
  f32x4 acc2[2][2] = {};
  #pragma unroll
  for (int ks = 0; ks < 4; ++ks) {
    const int k0 = ks * 32 + (lane >> 4) * 8;
    const short8v a0 = *(const short8v*)&Hs[(lane & 15)][k0];
    const short8v a1 = *(const short8v*)&Hs[16 + (lane & 15)][k0];
    const short8v bA = *(const short8v*)&w2p[((size_t)(ks * 8 + 2 * w) * 64 + lane) * 8];
    const short8v bB = *(const short8v*)&w2p[((size_t)(ks * 8 + 2 * w + 1) * 64 + lane) * 8];
    acc2[0][0] = __builtin_amdgcn_mfma_f32_16x16x32_bf16(a0, bA, acc2[0][0], 0, 0, 0);
    acc2[0][1] = __builtin_amdgcn_mfma_f32_16x16x32_bf16(a0, bB, acc2[0][1], 0, 0, 0);
    acc2[1][0] = __builtin_amdgcn_mfma_f32_16x16x32_bf16(a1, bA, acc2[1][0], 0, 0, 0);
    acc2[1][1] = __builtin_amdgcn_mfma_f32_16x16x32_bf16(a1, bB, acc2[1][1], 0, 0, 0);
  }
  float m0 = -3.4e38f, m1 = -3.4e38f;
  #pragma unroll
  for (int rt = 0; rt < 2; ++rt)
    #pragma unroll
    for (int reg = 0; reg < 4; ++reg) {
      m0 = fmaxf(m0, acc2[rt][0][reg]);
      m1 = fmaxf(m1, acc2[rt][1][reg]);
    }
  m0 += b2[32 * w + (lane & 15)];
  m1 += b2[32 * w + 16 + (lane & 15)];
  m0 = fmaxf(m0, __shfl_xor(m0, 16));
  m0 = fmaxf(m0, __shfl_xor(m0, 32));
  m1 = fmaxf(m1, __shfl_xor(m1, 16));
  m1 = fmaxf(m1, __shfl_xor(m1, 32));
  if (lane < 16) {
    out[(size_t)bs * CPATCH + 32 * w + lane]      = m0;
    out[(size_t)bs * CPATCH + 32 * w + 16 + lane] = m1;
  }
}

extern "C" void kernel_launch(void* const* d_in, const int* in_sizes, int n_in,
                              void* d_out, int out_size, void* d_ws, size_t ws_size,
                              hipStream_t stream) {
  const float* xyz = (const float*)d_in[0];
  const float* pf  = (const float*)d_in[1];
  const float* pc  = (const float*)d_in[2];
  const float* w1  = (const float*)d_in[3];
  const float* b1  = (const float*)d_in[4];
  const float* w2  = (const float*)d_in[5];
  const float* b2  = (const float*)d_in[6];

  float* out     = (float*)d_out;
  float* idx_out = out + (size_t)B_ * S_ * CPATCH;

  unsigned short* w1p = (unsigned short*)d_ws;          // 96*128 bf16 = 24 KB
  unsigned short* w2p = w1p + 96 * 128;                 // 128*128 bf16 = 32 KB

  pack_weights<<<14, 256, 0, stream>>>(w1, w2, w1p, w2p);
  ball_query_kernel<<<B_ * S_, 64, 0, stream>>>(xyz, pc, idx_out);
  patch_mlp_mfma<<<B_ * S_, 256, 0, stream>>>(xyz, pf, pc, w1p, b1, w2p, b2,
                                              idx_out, out);
}

// Round 3
// 53.899 us; speedup vs baseline: 9.6662x; 1.2267x over previous
//
#include <hip/hip_runtime.h>
#include <hip/hip_bf16.h>

#define B_ 8
#define N_ 16384
#define S_ 1024
#define K_ 32
#define CSTEM 64
#define CPATCH 128
#define INDIM 91
#define LDA 104   // LDS row stride (bf16) for A tile
#define LDH 136   // LDS row stride (bf16) for h1 tile

typedef __attribute__((ext_vector_type(8))) short short8v;  // 8 bf16 = 4 VGPRs
typedef __attribute__((ext_vector_type(4))) float f32x4;

static __device__ __forceinline__ unsigned short f2bf(float f) {
  union { float f; unsigned int u; } v; v.f = f;
  return (unsigned short)((v.u + 0x7FFFu + ((v.u >> 16) & 1u)) >> 16);  // RNE
}

// -------- Kernel 0: pack w1/w2 into MFMA B-fragment order (bf16) --------
__global__ __launch_bounds__(256) void pack_weights(
    const float* __restrict__ w1, const float* __restrict__ w2,
    unsigned short* __restrict__ w1p, unsigned short* __restrict__ w2p)
{
  const int id = blockIdx.x * 256 + threadIdx.x;
  if (id < 3 * 8 * 64) {                       // w1: K padded 91->96 (3 ksteps)
    const int l = id & 63, ct = (id >> 6) & 7, ks = id >> 9;
    const int col = 16 * ct + (l & 15);
    const int kb = 32 * ks + (l >> 4) * 8;
    unsigned short v[8];
    #pragma unroll
    for (int j = 0; j < 8; ++j) {
      const int k = kb + j;
      v[j] = (k < INDIM) ? f2bf(w1[k * CPATCH + col]) : (unsigned short)0;
    }
    *(short8v*)&w1p[(size_t)id * 8] = *(const short8v*)v;
  } else if (id < 3 * 8 * 64 + 4 * 8 * 64) {   // w2: 4 ksteps
    const int id2 = id - 3 * 8 * 64;
    const int l = id2 & 63, ct = (id2 >> 6) & 7, ks = id2 >> 9;
    const int col = 16 * ct + (l & 15);
    const int kb = 32 * ks + (l >> 4) * 8;
    unsigned short v[8];
    #pragma unroll
    for (int j = 0; j < 8; ++j) v[j] = f2bf(w2[(kb + j) * CPATCH + col]);
    *(short8v*)&w2p[(size_t)id2 * 8] = *(const short8v*)v;
  }
}

// -------- Kernel 1: ball query --------
// 4 queries per 256-thread block (1 wave per query, independent).
// Each lane processes 4 consecutive points per iteration (3x float4 loads).
// Distance math bit-identical to the verified R1 version (f64 on f32 values).
__global__ __launch_bounds__(256, 6) void ball_query_kernel(
    const float* __restrict__ xyz, const float* __restrict__ pc,
    float* __restrict__ idx_out)
{
  const int w    = threadIdx.x >> 6;
  const int lane = threadIdx.x & 63;
  const int bs   = blockIdx.x * 4 + w;           // b*S + s
  const int b    = bs >> 10;                     // S_ = 1024

  const float* __restrict__ xb = xyz + (size_t)b * N_ * 3;
  const double cx = (double)pc[bs * 3 + 0];
  const double cy = (double)pc[bs * 3 + 1];
  const double cz = (double)pc[bs * 3 + 2];
  const double rr = 0.2 * 0.2;

  __shared__ int fidx[4][K_];

  const unsigned long long lower = (1ull << lane) - 1ull;
  int found = 0;
  for (int base = 0; base < N_; base += 256) {
    const int i0 = base + lane * 4;
    const float4 p0 = *(const float4*)&xb[i0 * 3 + 0];   // x0 y0 z0 x1
    const float4 p1 = *(const float4*)&xb[i0 * 3 + 4];   // y1 z1 x2 y2
    const float4 p2 = *(const float4*)&xb[i0 * 3 + 8];   // z2 x3 y3 z3

    double dx, dy, dz;
    dx = (double)p0.x - cx; dy = (double)p0.y - cy; dz = (double)p0.z - cz;
    const bool in0 = (dx * dx + dy * dy + dz * dz) <= rr;
    dx = (double)p0.w - cx; dy = (double)p1.x - cy; dz = (double)p1.y - cz;
    const bool in1 = (dx * dx + dy * dy + dz * dz) <= rr;
    dx = (double)p1.z - cx; dy = (double)p1.w - cy; dz = (double)p2.x - cz;
    const bool in2 = (dx * dx + dy * dy + dz * dz) <= rr;
    dx = (double)p2.y - cx; dy = (double)p2.z - cy; dz = (double)p2.w - cz;
    const bool in3 = (dx * dx + dy * dy + dz * dz) <= rr;

    const unsigned long long b0 = __ballot(in0);
    const unsigned long long b1 = __ballot(in1);
    const unsigned long long b2 = __ballot(in2);
    const unsigned long long b3 = __ballot(in3);

    int p = found + __popcll(b0 & lower) + __popcll(b1 & lower)
                  + __popcll(b2 & lower) + __popcll(b3 & lower);
    if (in0) { if (p < K_) fidx[w][p] = i0 + 0; ++p; }
    if (in1) { if (p < K_) fidx[w][p] = i0 + 1; ++p; }
    if (in2) { if (p < K_) fidx[w][p] = i0 + 2; ++p; }
    if (in3) { if (p < K_) fidx[w][p] = i0 + 3; }

    found += __popcll(b0) + __popcll(b1) + __popcll(b2) + __popcll(b3);
    if (found >= K_) break;
  }
  __threadfence_block();   // drain LDS writes (wave-local, no barrier needed)
  if (lane < K_) {
    const int fill = (found == 0) ? (N_ - 1) : fidx[w][0];
    const int v = (lane < found) ? fidx[w][lane] : fill;
    idx_out[(size_t)bs * K_ + lane] = (float)v;
  }
}

// -------- Kernel 2: gather + PE + bf16-MFMA MLP + max (unchanged) --------
__global__ __launch_bounds__(256) void patch_mlp_mfma(
    const float* __restrict__ xyz, const float* __restrict__ pf,
    const float* __restrict__ pc,
    const unsigned short* __restrict__ w1p, const float* __restrict__ b1,
    const unsigned short* __restrict__ w2p, const float* __restrict__ b2,
    const float* __restrict__ idx_f, float* __restrict__ out)
{
  const int bs   = blockIdx.x;
  const int b    = bs >> 10;
  const int tid  = threadIdx.x;
  const int lane = tid & 63;
  const int w    = tid >> 6;

  __shared__ int sidx[K_];
  __shared__ float scen[3];
  __shared__ __align__(16) unsigned short As[K_][LDA];
  __shared__ __align__(16) unsigned short Hs[K_][LDH];

  if (tid < K_) sidx[tid] = (int)idx_f[(size_t)bs * K_ + tid];
  if (tid < 3)  scen[tid] = pc[bs * 3 + tid];
  __syncthreads();

  const float* __restrict__ pfb = pf  + (size_t)b * N_ * CSTEM;
  const float* __restrict__ xb  = xyz + (size_t)b * N_ * 3;

  {
    const int row = tid >> 3, sub = tid & 7;
    const int r = sidx[row];
    const float4 f0 = *(const float4*)&pfb[(size_t)r * CSTEM + sub * 8];
    const float4 f1 = *(const float4*)&pfb[(size_t)r * CSTEM + sub * 8 + 4];
    unsigned short v[8];
    v[0] = f2bf(f0.x); v[1] = f2bf(f0.y); v[2] = f2bf(f0.z); v[3] = f2bf(f0.w);
    v[4] = f2bf(f1.x); v[5] = f2bf(f1.y); v[6] = f2bf(f1.z); v[7] = f2bf(f1.w);
    *(short8v*)&As[row][sub * 8] = *(const short8v*)v;
  }
  {
    const int row = tid & 31, j = tid >> 5;
    const int r = sidx[row];
    float rel[3];
    rel[0] = xb[r * 3 + 0] - scen[0];
    rel[1] = xb[r * 3 + 1] - scen[1];
    rel[2] = xb[r * 3 + 2] - scen[2];
    #pragma unroll
    for (int cc = 0; cc < 4; ++cc) {
      const int c = 64 + 4 * j + cc;
      float val;
      if (c < 67) val = rel[c - 64];
      else if (c < 91) {
        const int q = c - 67, d = q >> 3, rbit = q & 7, band = rbit & 3;
        const float ang = rel[d] * ((float)(1 << band) * 3.14159265358979323846f);
        val = (rbit < 4) ? sinf(ang) : cosf(ang);
      } else val = 0.f;
      As[row][c] = f2bf(val);
    }
  }
  __syncthreads();

  f32x4 acc[2][2] = {};
  #pragma unroll
  for (int ks = 0; ks < 3; ++ks) {
    const int k0 = ks * 32 + (lane >> 4) * 8;
    const short8v a0 = *(const short8v*)&As[(lane & 15)][k0];
    const short8v a1 = *(const short8v*)&As[16 + (lane & 15)][k0];
    const short8v bA = *(const short8v*)&w1p[((size_t)(ks * 8 + 2 * w) * 64 + lane) * 8];
    const short8v bB = *(const short8v*)&w1p[((size_t)(ks * 8 + 2 * w + 1) * 64 + lane) * 8];
    acc[0][0] = __builtin_amdgcn_mfma_f32_16x16x32_bf16(a0, bA, acc[0][0], 0, 0, 0);
    acc[0][1] = __builtin_amdgcn_mfma_f32_16x16x32_bf16(a0, bB, acc[0][1], 0, 0, 0);
    acc[1][0] = __builtin_amdgcn_mfma_f32_16x16x32_bf16(a1, bA, acc[1][0], 0, 0, 0);
    acc[1][1] = __builtin_amdgcn_mfma_f32_16x16x32_bf16(a1, bB, acc[1][1], 0, 0, 0);
  }
  const float bias1[2] = { b1[32 * w + (lane & 15)], b1[32 * w + 16 + (lane & 15)] };
  #pragma unroll
  for (int rt = 0; rt < 2; ++rt)
    #pragma unroll
    for (int t = 0; t < 2; ++t)
      #pragma unroll
      for (int reg = 0; reg < 4; ++reg) {
        const float h = fmaxf(acc[rt][t][reg] + bias1[t], 0.f);
        const int row = 16 * rt + (lane >> 4) * 4 + reg;
        const int col = 32 * w + 16 * t + (lane & 15);
        Hs[row][col] = f2bf(h);
      }
  __syncthreads();

  f32x4 acc2[2][2] = {};
  #pragma unroll
  for (int ks = 0; ks < 4; ++ks) {
    const int k0 = ks * 32 + (lane >> 4) * 8;
    const short8v a0 = *(const short8v*)&Hs[(lane & 15)][k0];
    const short8v a1 = *(const short8v*)&Hs[16 + (lane & 15)][k0];
    const short8v bA = *(const short8v*)&w2p[((size_t)(ks * 8 + 2 * w) * 64 + lane) * 8];
    const short8v bB = *(const short8v*)&w2p[((size_t)(ks * 8 + 2 * w + 1) * 64 + lane) * 8];
    acc2[0][0] = __builtin_amdgcn_mfma_f32_16x16x32_bf16(a0, bA, acc2[0][0], 0, 0, 0);
    acc2[0][1] = __builtin_amdgcn_mfma_f32_16x16x32_bf16(a0, bB, acc2[0][1], 0, 0, 0);
    acc2[1][0] = __builtin_amdgcn_mfma_f32_16x16x32_bf16(a1, bA, acc2[1][0], 0, 0, 0);
    acc2[1][1] = __builtin_amdgcn_mfma_f32_16x16x32_bf16(a1, bB, acc2[1][1], 0, 0, 0);
  }
  float m0 = -3.4e38f, m1 = -3.4e38f;
  #pragma unroll
  for (int rt = 0; rt < 2; ++rt)
    #pragma unroll
    for (int reg = 0; reg < 4; ++reg) {
      m0 = fmaxf(m0, acc2[rt][0][reg]);
      m1 = fmaxf(m1, acc2[rt][1][reg]);
    }
  m0 += b2[32 * w + (lane & 15)];
  m1 += b2[32 * w + 16 + (lane & 15)];
  m0 = fmaxf(m0, __shfl_xor(m0, 16));
  m0 = fmaxf(m0, __shfl_xor(m0, 32));
  m1 = fmaxf(m1, __shfl_xor(m1, 16));
  m1 = fmaxf(m1, __shfl_xor(m1, 32));
  if (lane < 16) {
    out[(size_t)bs * CPATCH + 32 * w + lane]      = m0;
    out[(size_t)bs * CPATCH + 32 * w + 16 + lane] = m1;
  }
}

extern "C" void kernel_launch(void* const* d_in, const int* in_sizes, int n_in,
                              void* d_out, int out_size, void* d_ws, size_t ws_size,
                              hipStream_t stream) {
  const float* xyz = (const float*)d_in[0];
  const float* pf  = (const float*)d_in[1];
  const float* pc  = (const float*)d_in[2];
  const float* w1  = (const float*)d_in[3];
  const float* b1  = (const float*)d_in[4];
  const float* w2  = (const float*)d_in[5];
  const float* b2  = (const float*)d_in[6];

  float* out     = (float*)d_out;
  float* idx_out = out + (size_t)B_ * S_ * CPATCH;

  unsigned short* w1p = (unsigned short*)d_ws;
  unsigned short* w2p = w1p + 96 * 128;

  pack_weights<<<14, 256, 0, stream>>>(w1, w2, w1p, w2p);
  ball_query_kernel<<<B_ * S_ / 4, 256, 0, stream>>>(xyz, pc, idx_out);
  patch_mlp_mfma<<<B_ * S_, 256, 0, stream>>>(xyz, pf, pc, w1p, b1, w2p, b2,
                                              idx_out, out);
}